// Round 1
// baseline (889.808 us; speedup 1.0000x reference)
//
#include <hip/hip_runtime.h>
#include <stdint.h>

// ---------------------------------------------------------------------------
// AllPairsSimilarity: scores[q] = mean_n max_m ( qhat[q,n] . shat[m] )
//   qhat = q/||q||  (folded: invq applied AFTER max since invq>0)
//   shat = l2norm(mean_shots(support))
// GEMM: 128 x (1024x1024x640) bf16 MFMA, max fused into epilogue.
// ---------------------------------------------------------------------------

#define NQ   128
#define NP   1024   // patches (32*32)
#define C    640
#define NSH  5
#define EPSN 1e-12f

typedef __attribute__((ext_vector_type(8))) __bf16 bf16x8;
typedef __attribute__((ext_vector_type(4))) float  f32x4;

__device__ __forceinline__ unsigned short f2bf(float f) {
  unsigned int u = __builtin_bit_cast(unsigned int, f);
  unsigned int r = (u + 0x7fffu + ((u >> 16) & 1u)) >> 16;  // RNE
  return (unsigned short)r;
}

__device__ __forceinline__ void gload16(const void* g, void* l) {
  __builtin_amdgcn_global_load_lds(
      (const __attribute__((address_space(1))) void*)g,
      (__attribute__((address_space(3))) void*)l, 16, 0, 0);
}

// ---------------------------------------------------------------------------
// prep_s: proto = mean over shots; l2-normalize over c; write bf16 Sb[m][c]
// grid: 16 blocks x 256 threads, block handles 64 m
// ---------------------------------------------------------------------------
__global__ __launch_bounds__(256) void prep_s_kernel(
    const float* __restrict__ sup, unsigned short* __restrict__ Sb) {
  __shared__ float red[4][64];
  __shared__ float invn[64];
  int t = threadIdx.x;
  int tm = t & 63, tcg = t >> 6;
  int m = blockIdx.x * 64 + tm;

  float sumsq = 0.f;
  for (int c = tcg; c < C; c += 4) {
    float p = 0.f;
    #pragma unroll
    for (int s = 0; s < NSH; ++s) p += sup[((size_t)s * C + c) * NP + m];
    p *= 0.2f;
    sumsq += p * p;
  }
  red[tcg][tm] = sumsq;
  __syncthreads();
  if (t < 64) {
    float s = red[0][t] + red[1][t] + red[2][t] + red[3][t];
    invn[t] = 1.f / fmaxf(sqrtf(s), EPSN);
  }
  __syncthreads();
  float iv = invn[tm];
  for (int c = tcg; c < C; c += 4) {
    float p = 0.f;
    #pragma unroll
    for (int s = 0; s < NSH; ++s) p += sup[((size_t)s * C + c) * NP + m];
    p *= 0.2f;
    Sb[(size_t)m * C + c] = f2bf(p * iv);
  }
}

// ---------------------------------------------------------------------------
// prep_q: Qb[q][n][c] = bf16(Q[q][c][n]) (LDS tile transpose), invq[q][n]
// grid: (128, 16) x 256 threads; block = (q, 64-n slab)
// ---------------------------------------------------------------------------
__global__ __launch_bounds__(256) void prep_q_kernel(
    const float* __restrict__ Q, unsigned short* __restrict__ Qb,
    float* __restrict__ invq) {
  __shared__ float ld[64][65];
  __shared__ float red[4][64];
  int t = threadIdx.x;
  int q = blockIdx.x, nb = blockIdx.y;
  int n0 = nb * 64;
  int tn = t & 63, tcg = t >> 6;
  int tn2 = t >> 2, tq = t & 3;
  const float* qb = Q + (size_t)q * C * NP;
  unsigned short* ob = Qb + (size_t)q * NP * C;

  float sumsq = 0.f;
  for (int c0 = 0; c0 < C; c0 += 64) {
    #pragma unroll
    for (int it = 0; it < 16; ++it) {
      int c = c0 + tcg + 4 * it;
      float v = qb[(size_t)c * NP + n0 + tn];
      ld[c - c0][tn] = v;
      sumsq += v * v;
    }
    __syncthreads();
    unsigned short hb[16];
    #pragma unroll
    for (int j = 0; j < 16; ++j) hb[j] = f2bf(ld[tq * 16 + j][tn2]);
    uint4 w0, w1;
    w0.x = (unsigned)hb[0] | ((unsigned)hb[1] << 16);
    w0.y = (unsigned)hb[2] | ((unsigned)hb[3] << 16);
    w0.z = (unsigned)hb[4] | ((unsigned)hb[5] << 16);
    w0.w = (unsigned)hb[6] | ((unsigned)hb[7] << 16);
    w1.x = (unsigned)hb[8] | ((unsigned)hb[9] << 16);
    w1.y = (unsigned)hb[10] | ((unsigned)hb[11] << 16);
    w1.z = (unsigned)hb[12] | ((unsigned)hb[13] << 16);
    w1.w = (unsigned)hb[14] | ((unsigned)hb[15] << 16);
    unsigned short* dst = ob + (size_t)(n0 + tn2) * C + c0 + tq * 16;
    ((uint4*)dst)[0] = w0;
    ((uint4*)dst)[1] = w1;
    __syncthreads();
  }
  red[tcg][tn] = sumsq;
  __syncthreads();
  if (t < 64) {
    float s = red[0][t] + red[1][t] + red[2][t] + red[3][t];
    invq[(size_t)q * NP + n0 + t] = 1.f / fmaxf(sqrtf(s), EPSN);
  }
}

// ---------------------------------------------------------------------------
// gemm_max: block = (q, 128-n strip). Loop 8 m-tiles of 128; per tile K=640
// 16x16x32 bf16 MFMA, 128x128 tile, 4 waves (2x2), 4x4 frags each.
// Running max folded in registers; epilogue: xlane max -> LDS -> *invq -> sum.
// ---------------------------------------------------------------------------
__global__ __launch_bounds__(256, 2) void gemm_max_kernel(
    const unsigned short* __restrict__ Qb, const unsigned short* __restrict__ Sb,
    const float* __restrict__ invq, float* __restrict__ partial) {
  __shared__ __align__(16) unsigned short Qs[128 * 32];
  __shared__ __align__(16) unsigned short Ss[128 * 32];
  __shared__ float smax[2][128];
  __shared__ float ssum[4];

  int q = blockIdx.x, ns = blockIdx.y;
  int t = threadIdx.x;
  int lane = t & 63, wave = t >> 6;
  int wr = wave >> 1, wc = wave & 1;
  int l15 = lane & 15, quad = lane >> 4;
  int srow = t >> 2;           // 0..63 staging row
  int schunk = (t & 3) * 8;    // element offset within 32-wide row

  const unsigned short* qbase = Qb + ((size_t)q * NP + ns * 128) * C;

  f32x4 ninf = {-3.0e38f, -3.0e38f, -3.0e38f, -3.0e38f};
  f32x4 rm[4];
  #pragma unroll
  for (int i = 0; i < 4; ++i) rm[i] = ninf;

  for (int mt = 0; mt < 8; ++mt) {
    const unsigned short* sbase = Sb + (size_t)(mt * 128) * C;
    f32x4 zero = {0.f, 0.f, 0.f, 0.f};
    f32x4 acc[4][4];
    #pragma unroll
    for (int a = 0; a < 4; ++a)
      #pragma unroll
      for (int b = 0; b < 4; ++b) acc[a][b] = zero;

    for (int k0 = 0; k0 < C; k0 += 32) {
      const unsigned short* gq = qbase + (size_t)srow * C + k0 + schunk;
      const unsigned short* gs = sbase + (size_t)srow * C + k0 + schunk;
      gload16(gq,               (char*)Qs + t * 16);
      gload16(gq + (size_t)64 * C, (char*)Qs + 4096 + t * 16);
      gload16(gs,               (char*)Ss + t * 16);
      gload16(gs + (size_t)64 * C, (char*)Ss + 4096 + t * 16);
      __syncthreads();

      bf16x8 aF[4], bF[4];
      #pragma unroll
      for (int tr = 0; tr < 4; ++tr)
        aF[tr] = *(const bf16x8*)&Qs[(wr * 64 + tr * 16 + l15) * 32 + quad * 8];
      #pragma unroll
      for (int tc = 0; tc < 4; ++tc)
        bF[tc] = *(const bf16x8*)&Ss[(wc * 64 + tc * 16 + l15) * 32 + quad * 8];
      #pragma unroll
      for (int tr = 0; tr < 4; ++tr)
        #pragma unroll
        for (int tc = 0; tc < 4; ++tc)
          acc[tr][tc] = __builtin_amdgcn_mfma_f32_16x16x32_bf16(
              aF[tr], bF[tc], acc[tr][tc], 0, 0, 0);
      __syncthreads();
    }
    // fold this m-tile into running max (col-max within lane happens here;
    // cross-lane max over the 16 cols deferred to the end)
    #pragma unroll
    for (int tr = 0; tr < 4; ++tr)
      #pragma unroll
      for (int r = 0; r < 4; ++r) {
        float mv = fmaxf(fmaxf(acc[tr][0][r], acc[tr][1][r]),
                         fmaxf(acc[tr][2][r], acc[tr][3][r]));
        rm[tr][r] = fmaxf(rm[tr][r], mv);
      }
  }

  // cross-lane max over the 16 columns held by l15 (masks < 16 stay in quad)
  #pragma unroll
  for (int off = 8; off >= 1; off >>= 1)
    #pragma unroll
    for (int tr = 0; tr < 4; ++tr)
      #pragma unroll
      for (int r = 0; r < 4; ++r)
        rm[tr][r] = fmaxf(rm[tr][r], __shfl_xor(rm[tr][r], off, 64));

  if (l15 == 0) {
    #pragma unroll
    for (int tr = 0; tr < 4; ++tr)
      #pragma unroll
      for (int r = 0; r < 4; ++r)
        smax[wc][wr * 64 + tr * 16 + quad * 4 + r] = rm[tr][r];
  }
  __syncthreads();

  float v = 0.f;
  if (t < 128)
    v = fmaxf(smax[0][t], smax[1][t]) * invq[(size_t)q * NP + ns * 128 + t];
  #pragma unroll
  for (int off = 32; off >= 1; off >>= 1) v += __shfl_down(v, off, 64);
  if (lane == 0) ssum[wave] = v;
  __syncthreads();
  if (t == 0)
    partial[q * 8 + ns] = (ssum[0] + ssum[1] + ssum[2] + ssum[3]) * (1.f / 1024.f);
}

__global__ void reduce_out_kernel(const float* __restrict__ partial,
                                  float* __restrict__ out) {
  int t = threadIdx.x;  // 128
  float s = 0.f;
  #pragma unroll
  for (int i = 0; i < 8; ++i) s += partial[t * 8 + i];
  out[t] = s;
}

// ---------------------------------------------------------------------------
extern "C" void kernel_launch(void* const* d_in, const int* in_sizes, int n_in,
                              void* d_out, int out_size, void* d_ws, size_t ws_size,
                              hipStream_t stream) {
  const float* Q = (const float*)d_in[0];
  const float* S = (const float*)d_in[1];
  char* ws = (char*)d_ws;

  // ws layout (bytes):
  //   Qb   bf16 [128][1024][640]  = 167,772,160
  //   Sb   bf16 [1024][640]       =   1,310,720  @ 167,772,160
  //   invq f32  [128][1024]       =     524,288  @ 169,082,880
  //   part f32  [128][8]          =       4,096  @ 169,607,168
  unsigned short* Qb   = (unsigned short*)(ws);
  unsigned short* Sb   = (unsigned short*)(ws + 167772160ull);
  float*          invq = (float*)(ws + 169082880ull);
  float*          part = (float*)(ws + 169607168ull);
  float*          out  = (float*)d_out;

  prep_s_kernel<<<16, 256, 0, stream>>>(S, Sb);
  prep_q_kernel<<<dim3(128, 16), 256, 0, stream>>>(Q, Qb, invq);
  gemm_max_kernel<<<dim3(128, 8), 256, 0, stream>>>(Qb, Sb, invq, part);
  reduce_out_kernel<<<1, 128, 0, stream>>>(part, out);
}

// Round 2
// 796.377 us; speedup vs baseline: 1.1173x; 1.1173x over previous
//
#include <hip/hip_runtime.h>
#include <stdint.h>

// ---------------------------------------------------------------------------
// AllPairsSimilarity: scores[q] = mean_n max_m ( qhat[q,n] . shat[m] )
// R2: Q resident in registers (K-split wave pairs), prep_q fused into GEMM,
//     XOR-swizzled S staging (bank-conflict-free b-frag reads).
// Block = 256 thr = 4 waves = 2 pairs x (32 n) ; K halves of 320 per wave.
// Grid = (q=128, ns=16) ; n-strip 64 per block ; m-tiles 16 x 64.
// ---------------------------------------------------------------------------

#define NQ   128
#define NP   1024
#define C    640
#define NSH  5
#define KH   320
#define EPSN 1e-12f

typedef __attribute__((ext_vector_type(8))) __bf16 bf16x8;
typedef __attribute__((ext_vector_type(4))) float  f32x4;
typedef __attribute__((ext_vector_type(4))) unsigned int u32x4;

__device__ __forceinline__ unsigned short f2bf(float f) {
  unsigned int u = __builtin_bit_cast(unsigned int, f);
  unsigned int r = (u + 0x7fffu + ((u >> 16) & 1u)) >> 16;  // RNE
  return (unsigned short)r;
}

__device__ __forceinline__ void gload16(const void* g, void* l) {
  __builtin_amdgcn_global_load_lds(
      (const __attribute__((address_space(1))) void*)g,
      (__attribute__((address_space(3))) void*)l, 16, 0, 0);
}

// ---------------------------------------------------------------------------
// prep_s: proto = mean over shots; l2-normalize (fp32); write bf16 Sb[m][c]
// ---------------------------------------------------------------------------
__global__ __launch_bounds__(256) void prep_s_kernel(
    const float* __restrict__ sup, unsigned short* __restrict__ Sb) {
  __shared__ float red[4][64];
  __shared__ float invn[64];
  int t = threadIdx.x;
  int tm = t & 63, tcg = t >> 6;
  int m = blockIdx.x * 64 + tm;

  float sumsq = 0.f;
  for (int c = tcg; c < C; c += 4) {
    float p = 0.f;
    #pragma unroll
    for (int s = 0; s < NSH; ++s) p += sup[((size_t)s * C + c) * NP + m];
    p *= 0.2f;
    sumsq += p * p;
  }
  red[tcg][tm] = sumsq;
  __syncthreads();
  if (t < 64) {
    float s = red[0][t] + red[1][t] + red[2][t] + red[3][t];
    invn[t] = 1.f / fmaxf(sqrtf(s), EPSN);
  }
  __syncthreads();
  float iv = invn[tm];
  for (int c = tcg; c < C; c += 4) {
    float p = 0.f;
    #pragma unroll
    for (int s = 0; s < NSH; ++s) p += sup[((size_t)s * C + c) * NP + m];
    p *= 0.2f;
    Sb[(size_t)m * C + c] = f2bf(p * iv);
  }
}

// ---------------------------------------------------------------------------
// fused gemm: per block, load Q strip (64 n x 640 c fp32) once into A-frag
// registers (bf16) + invq (fp32), then stream all 16 m-tiles of S with max
// fused into the epilogue. K split across wave pairs (h=0: k<320, h=1: rest).
// ---------------------------------------------------------------------------
__global__ __launch_bounds__(256, 3) void fused_gemm_kernel(
    const float* __restrict__ Q, const unsigned short* __restrict__ Sb,
    float* __restrict__ partial) {
  // Region overlay:
  //  phase 1: qchunk [64 c][65 pad] fp32 (16640 B) ; qsums [16][64] f32 @16640
  //  phase 2: Ss 16 KB (2 halves x 64 rows x 8 x 16B, XOR-swizzled)
  //           pairbuf @16384: [2 pairs][8 frags][64 lanes x 16B]
  __shared__ __align__(16) char Rg[32768];
  __shared__ float invq[64];
  __shared__ float maxbuf[64];

  int t = threadIdx.x;
  int lane = t & 63, w = t >> 6;
  int p = w >> 1, h = w & 1;        // pair (n-sub), half (K-sub)
  int l15 = lane & 15, quad = lane >> 4;
  int q = blockIdx.x, ns = blockIdx.y;
  int n0 = ns * 64;

  // ---------------- Phase 1: Q strip -> aF regs + invq -------------------
  float* qchunk = (float*)Rg;                // [c][65]
  float* qsums  = (float*)(Rg + 16640);      // [16][64]

  bf16x8 aF[20];                             // (kstep 0..9) * 2 + nf
  f32x4 sq = {0.f, 0.f, 0.f, 0.f};
  int nq = t & 15, cg = t >> 4;
  const float* Qbase = Q + (size_t)q * C * NP + n0 + nq * 4;

  #pragma unroll
  for (int cc = 0; cc < 10; ++cc) {
    #pragma unroll
    for (int i = 0; i < 4; ++i) {
      int c = cg + i * 16;
      f32x4 v = *(const f32x4*)(Qbase + (size_t)(cc * 64 + c) * NP);
      sq += v * v;
      qchunk[c * 65 + nq * 4 + 0] = v[0];
      qchunk[c * 65 + nq * 4 + 1] = v[1];
      qchunk[c * 65 + nq * 4 + 2] = v[2];
      qchunk[c * 65 + nq * 4 + 3] = v[3];
    }
    __syncthreads();
    if ((h == 0) ? (cc < 5) : (cc >= 5)) {   // chunk in my K-half
      int ks0 = (cc % 5) * 2;                // cc const after unroll
      #pragma unroll
      for (int s = 0; s < 2; ++s) {
        #pragma unroll
        for (int nf = 0; nf < 2; ++nf) {
          int row = p * 32 + nf * 16 + l15;
          unsigned int uw[4];
          #pragma unroll
          for (int jj = 0; jj < 4; ++jj) {
            int k0 = s * 32 + quad * 8 + jj * 2;
            float v0 = qchunk[k0 * 65 + row];
            float v1 = qchunk[(k0 + 1) * 65 + row];
            uw[jj] = (unsigned)f2bf(v0) | ((unsigned)f2bf(v1) << 16);
          }
          u32x4 uu = {uw[0], uw[1], uw[2], uw[3]};
          aF[(ks0 + s) * 2 + nf] = __builtin_bit_cast(bf16x8, uu);
        }
      }
    }
    __syncthreads();
  }
  #pragma unroll
  for (int cm = 0; cm < 4; ++cm) qsums[cg * 64 + nq * 4 + cm] = sq[cm];
  __syncthreads();
  if (t < 64) {
    float s = 0.f;
    #pragma unroll
    for (int i = 0; i < 16; ++i) s += qsums[i * 64 + t];
    invq[t] = 1.f / fmaxf(sqrtf(s), EPSN);
  }
  __syncthreads();  // Rg free for reuse after this

  // ---------------- Phase 2: stream S m-tiles ----------------------------
  unsigned short* Ss = (unsigned short*)Rg;  // [H][row 64][chunk 8][8 bf16]
  char* pairbuf = Rg + 16384;

  f32x4 ninf = {-3.0e38f, -3.0e38f, -3.0e38f, -3.0e38f};
  f32x4 rm[2] = {ninf, ninf};

  for (int mt = 0; mt < 16; ++mt) {
    f32x4 zero = {0.f, 0.f, 0.f, 0.f};
    f32x4 acc[2][4];
    #pragma unroll
    for (int nf = 0; nf < 2; ++nf)
      #pragma unroll
      for (int mf = 0; mf < 4; ++mf) acc[nf][mf] = zero;

    #pragma unroll
    for (int j = 0; j < 5; ++j) {
      // stage 2 x (64 m x 64 k) bf16, XOR-swizzled 16B chunks
      #pragma unroll
      for (int i = 0; i < 4; ++i) {
        int H = i >> 1, ih = i & 1;
        int r = ih * 32 + w * 8 + (lane >> 3);
        int c = lane & 7;
        int cphys = c ^ (r & 7);
        const unsigned short* g =
            Sb + (size_t)(mt * 64 + r) * C + H * KH + j * 64 + cphys * 8;
        gload16(g, (char*)Ss + (size_t)(i * 256 + w * 64 + lane) * 16);
      }
      __syncthreads();
      #pragma unroll
      for (int s = 0; s < 2; ++s) {
        #pragma unroll
        for (int mf = 0; mf < 4; ++mf) {
          int row = mf * 16 + l15;
          int lc = s * 4 + quad;
          int cph = lc ^ (row & 7);
          bf16x8 b =
              *(const bf16x8*)((char*)Ss + h * 8192 + (row * 8 + cph) * 16);
          acc[0][mf] = __builtin_amdgcn_mfma_f32_16x16x32_bf16(
              aF[(j * 2 + s) * 2 + 0], b, acc[0][mf], 0, 0, 0);
          acc[1][mf] = __builtin_amdgcn_mfma_f32_16x16x32_bf16(
              aF[(j * 2 + s) * 2 + 1], b, acc[1][mf], 0, 0, 0);
        }
      }
      __syncthreads();
    }

    // combine K-halves within the pair, fold max (h==0 owns it)
    if (h == 1) {
      #pragma unroll
      for (int nf = 0; nf < 2; ++nf)
        #pragma unroll
        for (int mf = 0; mf < 4; ++mf)
          *(f32x4*)(pairbuf + (size_t)p * 8192 + (nf * 4 + mf) * 1024 +
                    lane * 16) = acc[nf][mf];
    }
    __syncthreads();
    if (h == 0) {
      #pragma unroll
      for (int nf = 0; nf < 2; ++nf) {
        #pragma unroll
        for (int mf = 0; mf < 4; ++mf) {
          f32x4 o = *(const f32x4*)(pairbuf + (size_t)p * 8192 +
                                    (nf * 4 + mf) * 1024 + lane * 16);
          f32x4 tot = acc[nf][mf] + o;
          #pragma unroll
          for (int r = 0; r < 4; ++r)
            rm[nf][r] = fmaxf(rm[nf][r], tot[r]);
        }
      }
    }
    // pairbuf reuse next mt is guarded by the 10 staging barriers
  }

  // ---------------- Epilogue ---------------------------------------------
  if (h == 0) {
    #pragma unroll
    for (int off = 8; off >= 1; off >>= 1)
      #pragma unroll
      for (int nf = 0; nf < 2; ++nf)
        #pragma unroll
        for (int r = 0; r < 4; ++r)
          rm[nf][r] = fmaxf(rm[nf][r], __shfl_xor(rm[nf][r], off, 64));
    if (l15 == 0) {
      #pragma unroll
      for (int nf = 0; nf < 2; ++nf)
        #pragma unroll
        for (int r = 0; r < 4; ++r)
          maxbuf[p * 32 + nf * 16 + quad * 4 + r] = rm[nf][r];
    }
  }
  __syncthreads();
  if (w == 0) {
    float v = maxbuf[lane] * invq[lane];
    #pragma unroll
    for (int off = 32; off >= 1; off >>= 1) v += __shfl_down(v, off, 64);
    if (lane == 0) partial[q * 16 + ns] = v * (1.f / 1024.f);
  }
}

__global__ void reduce_out_kernel(const float* __restrict__ partial,
                                  float* __restrict__ out) {
  int t = threadIdx.x;  // 128
  float s = 0.f;
  #pragma unroll
  for (int i = 0; i < 16; ++i) s += partial[t * 16 + i];
  out[t] = s;
}

// ---------------------------------------------------------------------------
extern "C" void kernel_launch(void* const* d_in, const int* in_sizes, int n_in,
                              void* d_out, int out_size, void* d_ws, size_t ws_size,
                              hipStream_t stream) {
  const float* Q = (const float*)d_in[0];
  const float* S = (const float*)d_in[1];
  char* ws = (char*)d_ws;

  // ws: Sb bf16 [1024][640] = 1,310,720 B ; partial f32 [128][16] @1,310,720
  unsigned short* Sb   = (unsigned short*)ws;
  float*          part = (float*)(ws + 1310720ull);
  float*          out  = (float*)d_out;

  prep_s_kernel<<<16, 256, 0, stream>>>(S, Sb);
  fused_gemm_kernel<<<dim3(128, 16), 256, 0, stream>>>(Q, Sb, part);
  reduce_out_kernel<<<1, 128, 0, stream>>>(part, out);
}

// Round 3
// 753.627 us; speedup vs baseline: 1.1807x; 1.0567x over previous
//
#include <hip/hip_runtime.h>
#include <stdint.h>

// ---------------------------------------------------------------------------
// AllPairsSimilarity: scores[q] = mean_n max_m ( qhat[q,n] . shat[m] )
// R3: n-partitioned waves (each wave: 32 n rows, FULL K=640 resident in
//     160 VGPRs of A-frags). No cross-wave combine. S staged k-major via
//     coalesced global_load_lds; every b128 B-read feeds 2 MFMA.
// Block = 256 thr = 4 waves x 32 n = 128-n strip. Grid = (q=128, ns=8).
// ---------------------------------------------------------------------------

#define NQ   128
#define NP   1024
#define C    640
#define NSH  5
#define EPSN 1e-12f

typedef __attribute__((ext_vector_type(8))) __bf16 bf16x8;
typedef __attribute__((ext_vector_type(4))) float  f32x4;
typedef __attribute__((ext_vector_type(4))) unsigned int u32x4;

__device__ __forceinline__ unsigned short f2bf(float f) {
  unsigned int u = __builtin_bit_cast(unsigned int, f);
  unsigned int r = (u + 0x7fffu + ((u >> 16) & 1u)) >> 16;  // RNE
  return (unsigned short)r;
}

__device__ __forceinline__ void gload16(const void* g, void* l) {
  __builtin_amdgcn_global_load_lds(
      (const __attribute__((address_space(1))) void*)g,
      (__attribute__((address_space(3))) void*)l, 16, 0, 0);
}

// ---------------------------------------------------------------------------
// prep_s: proto = mean over shots; l2-normalize (fp32); write bf16 k-major:
// Sb[k4][m][8] with k4 = c>>3  (so GEMM staging is lane-coalesced 16B chunks)
// ---------------------------------------------------------------------------
__global__ __launch_bounds__(256) void prep_s_kernel(
    const float* __restrict__ sup, unsigned short* __restrict__ Sb) {
  __shared__ float red[4][64];
  __shared__ float invn[64];
  int t = threadIdx.x;
  int tm = t & 63, tcg = t >> 6;
  int m = blockIdx.x * 64 + tm;

  float sumsq = 0.f;
  for (int c = tcg; c < C; c += 4) {
    float p = 0.f;
    #pragma unroll
    for (int s = 0; s < NSH; ++s) p += sup[((size_t)s * C + c) * NP + m];
    p *= 0.2f;
    sumsq += p * p;
  }
  red[tcg][tm] = sumsq;
  __syncthreads();
  if (t < 64) {
    float s = red[0][t] + red[1][t] + red[2][t] + red[3][t];
    invn[t] = 1.f / fmaxf(sqrtf(s), EPSN);
  }
  __syncthreads();
  float iv = invn[tm];
  for (int c = tcg; c < C; c += 4) {
    float p = 0.f;
    #pragma unroll
    for (int s = 0; s < NSH; ++s) p += sup[((size_t)s * C + c) * NP + m];
    p *= 0.2f;
    Sb[((size_t)(c >> 3) * 1024 + m) * 8 + (c & 7)] = f2bf(p * iv);
  }
}

// ---------------------------------------------------------------------------
// fused gemm
// ---------------------------------------------------------------------------
__global__ __launch_bounds__(256, 2) void fused_gemm_kernel(
    const float* __restrict__ Q, const unsigned short* __restrict__ Sb,
    float* __restrict__ partial) {
  // Rg overlay:
  //  phase 1: qchunk f32 [128 n][68]   = 34816 B ; qsums f32 [8][128] @34816
  //  phase 2: Ss bf16 [40 k4][64 m][8] = 40960 B
  __shared__ __align__(16) char Rg[40960];
  __shared__ float invq[128];
  __shared__ float maxbuf[128];
  __shared__ float ssum[2];

  const int t = threadIdx.x;
  const int lane = t & 63, w = t >> 6;
  const int l15 = lane & 15, quad = lane >> 4;
  const int q = blockIdx.x, ns = blockIdx.y;
  const int n0 = ns * 128;

  // ---------------- Phase 1: Q strip (128 n x 640 c) -> aF regs + invq ----
  float* qchunk = (float*)Rg;            // [n][68]
  float* qsums  = (float*)(Rg + 34816);  // [8][128]
  bf16x8 aF[40];                         // [ks 0..19][nf 0..1]
  const int nq = t & 31, cg = t >> 5;
  const float* Qbase = Q + (size_t)q * C * NP + n0 + nq * 4;
  const int arow = w * 32 + l15;
  f32x4 sq = {0.f, 0.f, 0.f, 0.f};

  #pragma unroll
  for (int cc = 0; cc < 10; ++cc) {
    #pragma unroll
    for (int i = 0; i < 8; ++i) {
      int c = cg + i * 8;
      f32x4 v = *(const f32x4*)(Qbase + (size_t)(cc * 64 + c) * NP);
      sq += v * v;
      #pragma unroll
      for (int j = 0; j < 4; ++j) qchunk[(nq * 4 + j) * 68 + c] = v[j];
    }
    __syncthreads();
    #pragma unroll
    for (int s = 0; s < 2; ++s) {
      #pragma unroll
      for (int nf = 0; nf < 2; ++nf) {
        int row = arow + nf * 16;
        unsigned int uw[4];
        #pragma unroll
        for (int jj = 0; jj < 4; ++jj) {
          int k0 = s * 32 + quad * 8 + jj * 2;
          float2 pr = *(const float2*)&qchunk[row * 68 + k0];
          uw[jj] = (unsigned)f2bf(pr.x) | ((unsigned)f2bf(pr.y) << 16);
        }
        u32x4 uu = {uw[0], uw[1], uw[2], uw[3]};
        aF[(cc * 2 + s) * 2 + nf] = __builtin_bit_cast(bf16x8, uu);
      }
    }
    __syncthreads();
  }
  #pragma unroll
  for (int j = 0; j < 4; ++j) qsums[cg * 128 + nq * 4 + j] = sq[j];
  __syncthreads();
  if (t < 128) {
    float s = 0.f;
    #pragma unroll
    for (int g = 0; g < 8; ++g) s += qsums[g * 128 + t];
    invq[t] = 1.f / fmaxf(sqrtf(s), EPSN);
  }
  __syncthreads();

  // ---------------- Phase 2: stream 16 m-tiles of 64 ----------------------
  unsigned short* Ss = (unsigned short*)Rg;  // [40 k4][64 m][8]
  f32x4 ninf = {-3.0e38f, -3.0e38f, -3.0e38f, -3.0e38f};
  f32x4 rm[2] = {ninf, ninf};

  for (int mt = 0; mt < 16; ++mt) {
    f32x4 zero = {0.f, 0.f, 0.f, 0.f};
    f32x4 acc[2][4];
    #pragma unroll
    for (int nf = 0; nf < 2; ++nf)
      #pragma unroll
      for (int mf = 0; mf < 4; ++mf) acc[nf][mf] = zero;

    #pragma unroll
    for (int h = 0; h < 2; ++h) {
      // stage 64 m x 320 k (k4 = h*40 + it*4 + w), fully coalesced
      const unsigned short* gsrc =
          Sb + ((size_t)(h * 40 + w) * 1024 + mt * 64 + lane) * 8;
      #pragma unroll
      for (int it = 0; it < 10; ++it)
        gload16(gsrc + (size_t)it * 32768, (char*)Ss + (it * 256 + t) * 16);
      __syncthreads();
      #pragma unroll
      for (int ks = 0; ks < 10; ++ks) {
        #pragma unroll
        for (int mf = 0; mf < 4; ++mf) {
          bf16x8 b = *(const bf16x8*)((char*)Ss +
              (size_t)(((ks * 4 + quad) * 64) + mf * 16 + l15) * 16);
          acc[0][mf] = __builtin_amdgcn_mfma_f32_16x16x32_bf16(
              aF[(h * 10 + ks) * 2 + 0], b, acc[0][mf], 0, 0, 0);
          acc[1][mf] = __builtin_amdgcn_mfma_f32_16x16x32_bf16(
              aF[(h * 10 + ks) * 2 + 1], b, acc[1][mf], 0, 0, 0);
        }
      }
      __syncthreads();
    }
    // fold m-tile into running max
    #pragma unroll
    for (int nf = 0; nf < 2; ++nf)
      #pragma unroll
      for (int r = 0; r < 4; ++r) {
        float mv = fmaxf(fmaxf(acc[nf][0][r], acc[nf][1][r]),
                         fmaxf(acc[nf][2][r], acc[nf][3][r]));
        rm[nf][r] = fmaxf(rm[nf][r], mv);
      }
  }

  // ---------------- Epilogue ----------------------------------------------
  #pragma unroll
  for (int off = 8; off >= 1; off >>= 1)
    #pragma unroll
    for (int nf = 0; nf < 2; ++nf)
      #pragma unroll
      for (int r = 0; r < 4; ++r)
        rm[nf][r] = fmaxf(rm[nf][r], __shfl_xor(rm[nf][r], off, 64));
  if (l15 == 0) {
    #pragma unroll
    for (int nf = 0; nf < 2; ++nf)
      #pragma unroll
      for (int r = 0; r < 4; ++r)
        maxbuf[w * 32 + nf * 16 + quad * 4 + r] = rm[nf][r];
  }
  __syncthreads();
  if (t < 128) {
    float v = maxbuf[t] * invq[t];
    #pragma unroll
    for (int off = 32; off >= 1; off >>= 1) v += __shfl_down(v, off, 64);
    if (lane == 0) ssum[w] = v;
  }
  __syncthreads();
  if (t == 0)
    partial[q * 8 + ns] = (ssum[0] + ssum[1]) * (1.f / 1024.f);
}

__global__ void reduce_out_kernel(const float* __restrict__ partial,
                                  float* __restrict__ out) {
  int t = threadIdx.x;  // 128
  float s = 0.f;
  #pragma unroll
  for (int i = 0; i < 8; ++i) s += partial[t * 8 + i];
  out[t] = s;
}

// ---------------------------------------------------------------------------
extern "C" void kernel_launch(void* const* d_in, const int* in_sizes, int n_in,
                              void* d_out, int out_size, void* d_ws, size_t ws_size,
                              hipStream_t stream) {
  const float* Q = (const float*)d_in[0];
  const float* S = (const float*)d_in[1];
  char* ws = (char*)d_ws;

  // ws: Sb bf16 k-major [80][1024][8] = 1,310,720 B ; partial f32 [128][8]
  unsigned short* Sb   = (unsigned short*)ws;
  float*          part = (float*)(ws + 1310720ull);
  float*          out  = (float*)d_out;

  prep_s_kernel<<<16, 256, 0, stream>>>(S, Sb);
  fused_gemm_kernel<<<dim3(128, 8), 256, 0, stream>>>(Q, Sb, part);
  reduce_out_kernel<<<1, 128, 0, stream>>>(part, out);
}

// Round 4
// 632.845 us; speedup vs baseline: 1.4060x; 1.1909x over previous
//
#include <hip/hip_runtime.h>
#include <stdint.h>

// ---------------------------------------------------------------------------
// AllPairsSimilarity: scores[q] = mean_n max_m ( qhat[q,n] . shat[m] )
// R4: same structure as R3 (wave-resident full-K A-frags, streamed S tiles)
// but phase-1 A-frag fill is template-unrolled with STATIC aF indices so the
// frags live in registers (R2/R3 spilled aF to scratch: 190 MB WRITE_SIZE).
// qchunk is c-major [c][132] (conflict-free b128 stores).
// Block = 256 thr = 4 waves x 32 n = 128-n strip. Grid = (q=128, ns=8).
// ---------------------------------------------------------------------------

#define NQ   128
#define NP   1024
#define C    640
#define NSH  5
#define EPSN 1e-12f
#define QPITCH 132   // dword pitch of qchunk rows (16B-aligned)

typedef __attribute__((ext_vector_type(8))) __bf16 bf16x8;
typedef __attribute__((ext_vector_type(4))) float  f32x4;
typedef __attribute__((ext_vector_type(4))) unsigned int u32x4;

__device__ __forceinline__ unsigned short f2bf(float f) {
  unsigned int u = __builtin_bit_cast(unsigned int, f);
  unsigned int r = (u + 0x7fffu + ((u >> 16) & 1u)) >> 16;  // RNE
  return (unsigned short)r;
}

__device__ __forceinline__ void gload16(const void* g, void* l) {
  __builtin_amdgcn_global_load_lds(
      (const __attribute__((address_space(1))) void*)g,
      (__attribute__((address_space(3))) void*)l, 16, 0, 0);
}

// ---------------------------------------------------------------------------
// prep_s: proto = mean over shots; l2-normalize (fp32); write bf16 k-major:
// Sb[k4][m][8], k4 = c>>3. Grid 64 blocks x 16 m.
// ---------------------------------------------------------------------------
__global__ __launch_bounds__(256) void prep_s_kernel(
    const float* __restrict__ sup, unsigned short* __restrict__ Sb) {
  __shared__ float red[16][17];
  __shared__ float invn[16];
  int t = threadIdx.x;
  int tm = t & 15, tcg = t >> 4;   // 16 c-groups
  int m = blockIdx.x * 16 + tm;

  float sumsq = 0.f;
  for (int c = tcg; c < C; c += 16) {
    float p = 0.f;
    #pragma unroll
    for (int s = 0; s < NSH; ++s) p += sup[((size_t)s * C + c) * NP + m];
    p *= 0.2f;
    sumsq += p * p;
  }
  red[tcg][tm] = sumsq;
  __syncthreads();
  if (t < 16) {
    float s = 0.f;
    #pragma unroll
    for (int g = 0; g < 16; ++g) s += red[g][t];
    invn[t] = 1.f / fmaxf(sqrtf(s), EPSN);
  }
  __syncthreads();
  float iv = invn[tm];
  for (int c = tcg; c < C; c += 16) {
    float p = 0.f;
    #pragma unroll
    for (int s = 0; s < NSH; ++s) p += sup[((size_t)s * C + c) * NP + m];
    p *= 0.2f;
    Sb[((size_t)(c >> 3) * 1024 + m) * 8 + (c & 7)] = f2bf(p * iv);
  }
}

// ---------------------------------------------------------------------------
// phase-1 step: stage 64 c-rows of Q (fp32, c-major in LDS), build the 4
// A-frags for k-steps 2*CC and 2*CC+1 with compile-time destinations.
// ---------------------------------------------------------------------------
template <int CC>
__device__ __forceinline__ void q_step(const float* __restrict__ Qbase,
                                       float* __restrict__ qchunk,
                                       f32x4& sq, int nq, int cg, int arow,
                                       int quad,
                                       bf16x8& f00, bf16x8& f01,
                                       bf16x8& f10, bf16x8& f11) {
  #pragma unroll
  for (int i = 0; i < 8; ++i) {
    int c = cg + i * 8;
    f32x4 v = *(const f32x4*)(Qbase + (size_t)(CC * 64 + c) * NP);
    sq += v * v;
    *(f32x4*)&qchunk[c * QPITCH + nq * 4] = v;
  }
  __syncthreads();
  #pragma unroll
  for (int s = 0; s < 2; ++s) {
    #pragma unroll
    for (int nf = 0; nf < 2; ++nf) {
      int row = arow + nf * 16;
      unsigned int uw[4];
      #pragma unroll
      for (int jj = 0; jj < 4; ++jj) {
        int k0 = s * 32 + quad * 8 + jj * 2;
        float v0 = qchunk[k0 * QPITCH + row];
        float v1 = qchunk[(k0 + 1) * QPITCH + row];
        uw[jj] = (unsigned)f2bf(v0) | ((unsigned)f2bf(v1) << 16);
      }
      u32x4 uu = {uw[0], uw[1], uw[2], uw[3]};
      bf16x8 r = __builtin_bit_cast(bf16x8, uu);
      if (s == 0 && nf == 0) f00 = r;
      else if (s == 0 && nf == 1) f01 = r;
      else if (s == 1 && nf == 0) f10 = r;
      else f11 = r;
    }
  }
  __syncthreads();
}

// ---------------------------------------------------------------------------
// fused gemm
// ---------------------------------------------------------------------------
__global__ __launch_bounds__(256, 2) void fused_gemm_kernel(
    const float* __restrict__ Q, const unsigned short* __restrict__ Sb,
    float* __restrict__ partial) {
  // Rg overlay:
  //  phase 1: qchunk f32 [64 c][QPITCH] = 33792 B ; qsums f32 [8][128] @33792
  //  phase 2: Ss bf16 [40 k4][64 m][8]  = 40960 B
  __shared__ __align__(16) char Rg[40960];
  __shared__ float invq[128];
  __shared__ float maxbuf[128];
  __shared__ float ssum[2];

  const int t = threadIdx.x;
  const int lane = t & 63, w = t >> 6;
  const int l15 = lane & 15, quad = lane >> 4;
  const int q = blockIdx.x, ns = blockIdx.y;
  const int n0 = ns * 128;

  // ---------------- Phase 1: Q strip (128 n x 640 c) -> aF regs + invq ----
  float* qchunk = (float*)Rg;            // [c][QPITCH]
  float* qsums  = (float*)(Rg + 33792);  // [8][128]
  bf16x8 aF[40];                         // [ks 0..19][nf 0..1], STATIC idx only
  const int nq = t & 31, cg = t >> 5;
  const float* Qbase = Q + (size_t)q * C * NP + n0 + nq * 4;
  const int arow = w * 32 + l15;
  f32x4 sq = {0.f, 0.f, 0.f, 0.f};

  q_step<0>(Qbase, qchunk, sq, nq, cg, arow, quad, aF[0],  aF[1],  aF[2],  aF[3]);
  q_step<1>(Qbase, qchunk, sq, nq, cg, arow, quad, aF[4],  aF[5],  aF[6],  aF[7]);
  q_step<2>(Qbase, qchunk, sq, nq, cg, arow, quad, aF[8],  aF[9],  aF[10], aF[11]);
  q_step<3>(Qbase, qchunk, sq, nq, cg, arow, quad, aF[12], aF[13], aF[14], aF[15]);
  q_step<4>(Qbase, qchunk, sq, nq, cg, arow, quad, aF[16], aF[17], aF[18], aF[19]);
  q_step<5>(Qbase, qchunk, sq, nq, cg, arow, quad, aF[20], aF[21], aF[22], aF[23]);
  q_step<6>(Qbase, qchunk, sq, nq, cg, arow, quad, aF[24], aF[25], aF[26], aF[27]);
  q_step<7>(Qbase, qchunk, sq, nq, cg, arow, quad, aF[28], aF[29], aF[30], aF[31]);
  q_step<8>(Qbase, qchunk, sq, nq, cg, arow, quad, aF[32], aF[33], aF[34], aF[35]);
  q_step<9>(Qbase, qchunk, sq, nq, cg, arow, quad, aF[36], aF[37], aF[38], aF[39]);

  #pragma unroll
  for (int j = 0; j < 4; ++j) qsums[cg * 128 + nq * 4 + j] = sq[j];
  __syncthreads();
  if (t < 128) {
    float s = 0.f;
    #pragma unroll
    for (int g = 0; g < 8; ++g) s += qsums[g * 128 + t];
    invq[t] = 1.f / fmaxf(sqrtf(s), EPSN);
  }
  __syncthreads();

  // ---------------- Phase 2: stream 16 m-tiles of 64 ----------------------
  unsigned short* Ss = (unsigned short*)Rg;  // [40 k4][64 m][8]
  f32x4 ninf = {-3.0e38f, -3.0e38f, -3.0e38f, -3.0e38f};
  f32x4 rm[2] = {ninf, ninf};

  for (int mt = 0; mt < 16; ++mt) {
    f32x4 zero = {0.f, 0.f, 0.f, 0.f};
    f32x4 acc[2][4];
    #pragma unroll
    for (int nf = 0; nf < 2; ++nf)
      #pragma unroll
      for (int mf = 0; mf < 4; ++mf) acc[nf][mf] = zero;

    #pragma unroll
    for (int h = 0; h < 2; ++h) {
      // stage 64 m x 320 k (k4 = h*40 + it*4 + w), fully coalesced
      const unsigned short* gsrc =
          Sb + ((size_t)(h * 40 + w) * 1024 + mt * 64 + lane) * 8;
      #pragma unroll
      for (int it = 0; it < 10; ++it)
        gload16(gsrc + (size_t)it * 32768, (char*)Ss + (it * 256 + t) * 16);
      __syncthreads();
      #pragma unroll
      for (int ks = 0; ks < 10; ++ks) {
        #pragma unroll
        for (int mf = 0; mf < 4; ++mf) {
          bf16x8 b = *(const bf16x8*)((char*)Ss +
              (size_t)(((ks * 4 + quad) * 64) + mf * 16 + l15) * 16);
          acc[0][mf] = __builtin_amdgcn_mfma_f32_16x16x32_bf16(
              aF[(h * 10 + ks) * 2 + 0], b, acc[0][mf], 0, 0, 0);
          acc[1][mf] = __builtin_amdgcn_mfma_f32_16x16x32_bf16(
              aF[(h * 10 + ks) * 2 + 1], b, acc[1][mf], 0, 0, 0);
        }
      }
      __syncthreads();
    }
    // fold m-tile into running max
    #pragma unroll
    for (int nf = 0; nf < 2; ++nf)
      #pragma unroll
      for (int r = 0; r < 4; ++r) {
        float mv = fmaxf(fmaxf(acc[nf][0][r], acc[nf][1][r]),
                         fmaxf(acc[nf][2][r], acc[nf][3][r]));
        rm[nf][r] = fmaxf(rm[nf][r], mv);
      }
  }

  // ---------------- Epilogue ----------------------------------------------
  #pragma unroll
  for (int off = 8; off >= 1; off >>= 1)
    #pragma unroll
    for (int nf = 0; nf < 2; ++nf)
      #pragma unroll
      for (int r = 0; r < 4; ++r)
        rm[nf][r] = fmaxf(rm[nf][r], __shfl_xor(rm[nf][r], off, 64));
  if (l15 == 0) {
    #pragma unroll
    for (int nf = 0; nf < 2; ++nf)
      #pragma unroll
      for (int r = 0; r < 4; ++r)
        maxbuf[w * 32 + nf * 16 + quad * 4 + r] = rm[nf][r];
  }
  __syncthreads();
  if (t < 128) {
    float v = maxbuf[t] * invq[t];
    #pragma unroll
    for (int off = 32; off >= 1; off >>= 1) v += __shfl_down(v, off, 64);
    if (lane == 0) ssum[w] = v;
  }
  __syncthreads();
  if (t == 0)
    partial[q * 8 + ns] = (ssum[0] + ssum[1]) * (1.f / 1024.f);
}

__global__ void reduce_out_kernel(const float* __restrict__ partial,
                                  float* __restrict__ out) {
  int t = threadIdx.x;  // 128
  float s = 0.f;
  #pragma unroll
  for (int i = 0; i < 8; ++i) s += partial[t * 8 + i];
  out[t] = s;
}

// ---------------------------------------------------------------------------
extern "C" void kernel_launch(void* const* d_in, const int* in_sizes, int n_in,
                              void* d_out, int out_size, void* d_ws, size_t ws_size,
                              hipStream_t stream) {
  const float* Q = (const float*)d_in[0];
  const float* S = (const float*)d_in[1];
  char* ws = (char*)d_ws;

  // ws: Sb bf16 k-major [80][1024][8] = 1,310,720 B ; partial f32 [128][8]
  unsigned short* Sb   = (unsigned short*)ws;
  float*          part = (float*)(ws + 1310720ull);
  float*          out  = (float*)d_out;

  prep_s_kernel<<<64, 256, 0, stream>>>(S, Sb);
  fused_gemm_kernel<<<dim3(128, 8), 256, 0, stream>>>(Q, Sb, part);
  reduce_out_kernel<<<1, 128, 0, stream>>>(part, out);
}